// Round 1
// baseline (1849.694 us; speedup 1.0000x reference)
//
#include <hip/hip_runtime.h>

#define N_NODES 100000
#define N_EDGES 3200000
#define K_IN    1433
#define HID     16
#define OUTF    7

#define NCHUNK  23            // ceil(1433/64)
#define ROWS_PER_BLOCK 64

typedef float f4 __attribute__((ext_vector_type(4)));

// feature rows are only 4B-aligned (1433 floats/row) -> memcpy-based 16B load,
// lowers to global_load_dwordx4 with align(4) which is legal on gfx9+.
__device__ __forceinline__ f4 load_f4_align4(const float* p) {
    f4 r;
    __builtin_memcpy(&r, p, sizeof(f4));
    return r;
}

// ---------------- degree + norm ----------------
__global__ void deg_kernel(const int* __restrict__ ei,
                           float* __restrict__ deg_out, float* __restrict__ deg_in) {
    int e = blockIdx.x * blockDim.x + threadIdx.x;
    if (e < N_EDGES) {
        atomicAdd(&deg_out[ei[e]], 1.0f);
        atomicAdd(&deg_in[ei[N_EDGES + e]], 1.0f);
    }
}

__global__ void norm_kernel(float* __restrict__ nsrc, float* __restrict__ ndst) {
    int i = blockIdx.x * blockDim.x + threadIdx.x;
    if (i < N_NODES) {
        nsrc[i] = rsqrtf(fmaxf(nsrc[i], 1.0f));
        ndst[i] = rsqrtf(fmaxf(ndst[i], 1.0f));
    }
}

// ---------------- layer-1 GEMM: x1 = (feat * nsrc) @ W1 ----------------
// block = 256 threads = 16 cols (c) x 16 K-slices (ks). W1 slice lives in
// 92 VGPRs per thread; feat streamed straight from global (coalesced across
// the wave: lanes cover contiguous 256B per chunk). Wave-partial reduced via
// shfl_xor over the 4 in-wave ks groups, then atomicAdd into zeroed x1
// (4 waves/block contribute independently -> no barriers).
__global__ __launch_bounds__(256) void gemm1_kernel(
    const float* __restrict__ feat, const float* __restrict__ W1,
    const float* __restrict__ norm_src, float* __restrict__ x1)
{
    const int tid = threadIdx.x;
    const int c   = tid & 15;
    const int ks  = tid >> 4;     // 0..15
    const int k0  = 4 * ks;       // offset inside each 64-wide chunk

    f4 w[NCHUNK];
#pragma unroll
    for (int i = 0; i < NCHUNK - 1; ++i) {
        int k = 64 * i + k0;
        w[i].x = W1[(k + 0) * HID + c];
        w[i].y = W1[(k + 1) * HID + c];
        w[i].z = W1[(k + 2) * HID + c];
        w[i].w = W1[(k + 3) * HID + c];
    }
    {
        int k = 64 * (NCHUNK - 1) + k0;
        w[NCHUNK - 1].x = (k + 0 < K_IN) ? W1[(k + 0) * HID + c] : 0.0f;
        w[NCHUNK - 1].y = (k + 1 < K_IN) ? W1[(k + 1) * HID + c] : 0.0f;
        w[NCHUNK - 1].z = (k + 2 < K_IN) ? W1[(k + 2) * HID + c] : 0.0f;
        w[NCHUNK - 1].w = (k + 3 < K_IN) ? W1[(k + 3) * HID + c] : 0.0f;
    }

    const int row0 = blockIdx.x * ROWS_PER_BLOCK;
    const int row1 = min(row0 + ROWS_PER_BLOCK, N_NODES);
    for (int row = row0; row < row1; ++row) {
        const float* fr = feat + (size_t)row * K_IN + k0;
        float acc[4] = {0.f, 0.f, 0.f, 0.f};
#pragma unroll
        for (int i = 0; i < NCHUNK - 1; ++i) {
            f4 f = load_f4_align4(fr + 64 * i);
            acc[i & 3] += f.x * w[i].x + f.y * w[i].y + f.z * w[i].z + f.w * w[i].w;
        }
        {   // guarded tail chunk (k = 1408 + k0 + j)
            const int kb = 64 * (NCHUNK - 1);
            float t = 0.f;
            if (kb + k0 + 0 < K_IN) t += fr[kb + 0] * w[NCHUNK - 1].x;
            if (kb + k0 + 1 < K_IN) t += fr[kb + 1] * w[NCHUNK - 1].y;
            if (kb + k0 + 2 < K_IN) t += fr[kb + 2] * w[NCHUNK - 1].z;
            if (kb + k0 + 3 < K_IN) t += fr[kb + 3] * w[NCHUNK - 1].w;
            acc[3] += t;
        }
        float a = (acc[0] + acc[1]) + (acc[2] + acc[3]);
        a += __shfl_xor(a, 16, 64);   // combine ks pairs
        a += __shfl_xor(a, 32, 64);   // all 4 in-wave ks groups
        if ((tid & 63) < 16) {
            atomicAdd(&x1[(size_t)row * HID + c], a * norm_src[row]);
        }
    }
}

// ---------------- edge scatter, layer 1: m1[dst] += x1[src] ----------------
__global__ void scatter1_kernel(const int* __restrict__ ei,
                                const float* __restrict__ x1, float* __restrict__ m1) {
    int t = blockIdx.x * blockDim.x + threadIdx.x;
    if (t < N_EDGES * HID) {
        int e = t >> 4, j = t & 15;
        int s = ei[e];
        int d = ei[N_EDGES + e];
        atomicAdd(&m1[(size_t)d * HID + j], x1[(size_t)s * HID + j]);
    }
}

// ---- layer-1 epilogue fused with layer-2 dense: x2 = (relu(m1*ndst+b1)*nsrc) @ W2
__global__ void layer2_kernel(const float* __restrict__ m1,
                              const float* __restrict__ nsrc, const float* __restrict__ ndst,
                              const float* __restrict__ W2, const float* __restrict__ b1,
                              float* __restrict__ x2) {
    int i = blockIdx.x * blockDim.x + threadIdx.x;
    if (i >= N_NODES) return;
    float nd = ndst[i], ns = nsrc[i];
    float h[HID];
#pragma unroll
    for (int j = 0; j < HID; ++j)
        h[j] = fmaxf(m1[(size_t)i * HID + j] * nd + b1[j], 0.0f);
#pragma unroll
    for (int cc = 0; cc < OUTF; ++cc) {
        float a = 0.f;
#pragma unroll
        for (int j = 0; j < HID; ++j) a += h[j] * W2[j * OUTF + cc];
        x2[(size_t)i * OUTF + cc] = a * ns;
    }
}

// ---------------- edge scatter, layer 2: out[dst] += x2[src] ----------------
__global__ void scatter2_kernel(const int* __restrict__ ei,
                                const float* __restrict__ x2, float* __restrict__ out) {
    int t = blockIdx.x * blockDim.x + threadIdx.x;
    if (t < N_EDGES * 8) {
        int e = t >> 3, j = t & 7;
        if (j < OUTF) {
            int s = ei[e];
            int d = ei[N_EDGES + e];
            atomicAdd(&out[(size_t)d * OUTF + j], x2[(size_t)s * OUTF + j]);
        }
    }
}

// ---------------- final epilogue: out = out * ndst + b2 ----------------
__global__ void final_kernel(float* __restrict__ out, const float* __restrict__ ndst,
                             const float* __restrict__ b2) {
    int t = blockIdx.x * blockDim.x + threadIdx.x;
    if (t < N_NODES * 8) {
        int i = t >> 3, j = t & 7;
        if (j < OUTF) {
            size_t idx = (size_t)i * OUTF + j;
            out[idx] = out[idx] * ndst[i] + b2[j];
        }
    }
}

extern "C" void kernel_launch(void* const* d_in, const int* in_sizes, int n_in,
                              void* d_out, int out_size, void* d_ws, size_t ws_size,
                              hipStream_t stream) {
    const float* feat = (const float*)d_in[0];
    const int*   ei   = (const int*)d_in[1];     // [2, E] int32
    const float* W1   = (const float*)d_in[2];   // [1433,16]
    const float* b1   = (const float*)d_in[3];
    const float* W2   = (const float*)d_in[4];   // [16,7]
    const float* b2   = (const float*)d_in[5];
    float*       out  = (float*)d_out;           // [N,7]

    // workspace layout (floats): [nsrc N][ndst N][m1 16N][x1/x2 16N] = 34N
    float* ws   = (float*)d_ws;
    float* nsrc = ws;
    float* ndst = ws + N_NODES;
    float* m1   = ws + 2 * (size_t)N_NODES;
    float* x1   = ws + 18 * (size_t)N_NODES;
    float* x2   = x1;  // x1 dead after scatter1; reuse for x2 (stride 7)

    // zero: degrees, m1, x1 (gemm1 atomically accumulates), and d_out
    hipMemsetAsync(ws, 0, (size_t)34 * N_NODES * sizeof(float), stream);
    hipMemsetAsync(d_out, 0, (size_t)N_NODES * OUTF * sizeof(float), stream);

    deg_kernel<<<(N_EDGES + 255) / 256, 256, 0, stream>>>(ei, nsrc, ndst);
    norm_kernel<<<(N_NODES + 255) / 256, 256, 0, stream>>>(nsrc, ndst);
    gemm1_kernel<<<(N_NODES + ROWS_PER_BLOCK - 1) / ROWS_PER_BLOCK, 256, 0, stream>>>(
        feat, W1, nsrc, x1);
    scatter1_kernel<<<(N_EDGES * HID + 255) / 256, 256, 0, stream>>>(ei, x1, m1);
    layer2_kernel<<<(N_NODES + 255) / 256, 256, 0, stream>>>(m1, nsrc, ndst, W2, b1, x2);
    scatter2_kernel<<<(N_EDGES * 8 + 255) / 256, 256, 0, stream>>>(ei, x2, out);
    final_kernel<<<(N_NODES * 8 + 255) / 256, 256, 0, stream>>>(out, ndst, b2);
}

// Round 2
// 1545.867 us; speedup vs baseline: 1.1965x; 1.1965x over previous
//
#include <hip/hip_runtime.h>

#define NN   100000
#define NE   3200000
#define K_IN 1433
#define HID  16
#define OUTF 7

typedef float f4 __attribute__((ext_vector_type(4)));

__device__ __forceinline__ f4 ld_f4u(const float* p) { f4 r; __builtin_memcpy(&r, p, 16); return r; }
__device__ __forceinline__ void st_f4u(float* p, f4 v) { __builtin_memcpy(p, &v, 16); }

// ---------------- CSR build ----------------
__global__ void count_kernel(const int* __restrict__ ei,
                             int* __restrict__ cnt_src, int* __restrict__ cnt_dst) {
    int e = blockIdx.x * blockDim.x + threadIdx.x;
    if (e < NE) {
        atomicAdd(&cnt_src[ei[e]], 1);
        atomicAdd(&cnt_dst[ei[NE + e]], 1);
    }
}

__global__ void norm_kernel(const int* __restrict__ cnt_src, const int* __restrict__ cnt_dst,
                            float* __restrict__ nsrc, float* __restrict__ ndst) {
    int i = blockIdx.x * blockDim.x + threadIdx.x;
    if (i < NN) {
        nsrc[i] = rsqrtf(fmaxf((float)cnt_src[i], 1.0f));
        ndst[i] = rsqrtf(fmaxf((float)cnt_dst[i], 1.0f));
    }
}

// single-block exclusive scan of cnt_dst -> offs (+ copy to cursor)
__global__ __launch_bounds__(1024) void scan_kernel(const int* __restrict__ cnt,
                                                    int* __restrict__ offs, int* __restrict__ cursor) {
    __shared__ int wsums[16];
    const int tid = threadIdx.x, lane = tid & 63, wv = tid >> 6;
    int carry = 0;
    for (int base = 0; base < NN; base += 1024) {
        int i = base + tid;
        int v = (i < NN) ? cnt[i] : 0;
        int s = v;
#pragma unroll
        for (int d = 1; d < 64; d <<= 1) { int t = __shfl_up(s, d, 64); if (lane >= d) s += t; }
        if (lane == 63) wsums[wv] = s;
        __syncthreads();
        int wexcl = 0, total = 0;
#pragma unroll
        for (int j = 0; j < 16; ++j) { int wj = wsums[j]; if (j < wv) wexcl += wj; total += wj; }
        int excl = carry + wexcl + (s - v);
        if (i < NN) { offs[i] = excl; cursor[i] = excl; }
        carry += total;
        __syncthreads();
    }
}

__global__ void fill_kernel(const int* __restrict__ ei, int* __restrict__ cursor,
                            int* __restrict__ sorted_src) {
    int e = blockIdx.x * blockDim.x + threadIdx.x;
    if (e < NE) {
        int d = ei[NE + e];
        int slot = atomicAdd(&cursor[d], 1);
        sorted_src[slot] = ei[e];
    }
}

// ---------------- layer-1 GEMM: x1 = (feat * nsrc) @ W1 ----------------
// Block = 4 waves; wave w owns cols [4w,4w+4). Lane l owns k in {4l+256i}.
// Each wave's 64 lanes load 64 DISTINCT f4s per instr (1KB coalesced).
// W1 slice: 96 VGPRs/thread. Per-row reduction: 7-shuffle value-folding
// butterfly; disjoint direct stores (no atomics, no zero-init of x1).
__global__ __launch_bounds__(256, 3) void gemm1_kernel(
    const float* __restrict__ feat, const float* __restrict__ W1,
    const float* __restrict__ nsrc, float* __restrict__ x1, int rows_per_block)
{
    const int tid  = threadIdx.x;
    const int lane = tid & 63;
    const int wv   = tid >> 6;
    const int c0   = 4 * wv;

    const int kb5 = 1280 + 4 * lane;                       // i=5 nominal base
    const int kc5 = (kb5 > K_IN - 4) ? (K_IN - 4) : kb5;   // clamped (in-row) load base

    f4 w[6][4];
#pragma unroll
    for (int i = 0; i < 5; ++i) {
        int kb = 4 * lane + 256 * i;
#pragma unroll
        for (int d = 0; d < 4; ++d)
            w[i][d] = ld_f4u(W1 + (size_t)(kb + d) * HID + c0);
    }
#pragma unroll
    for (int d = 0; d < 4; ++d) {
        int keff = kc5 + d;
        f4 z = {0.f, 0.f, 0.f, 0.f};
        w[5][d] = (keff >= kb5 && keff < K_IN) ? ld_f4u(W1 + (size_t)keff * HID + c0) : z;
    }

    int row0 = blockIdx.x * rows_per_block;
    int row1 = min(row0 + rows_per_block, NN);
    if (row0 >= row1) return;

    f4 f[6], g[6];
    const float* fp = feat + (size_t)row0 * K_IN;
#pragma unroll
    for (int i = 0; i < 5; ++i) f[i] = ld_f4u(fp + 4 * lane + 256 * i);
    f[5] = ld_f4u(fp + kc5);

    for (int row = row0; row < row1; ++row) {
        if (row + 1 < row1) {                       // prefetch next row
            const float* gp = feat + (size_t)(row + 1) * K_IN;
#pragma unroll
            for (int i = 0; i < 5; ++i) g[i] = ld_f4u(gp + 4 * lane + 256 * i);
            g[5] = ld_f4u(gp + kc5);
        }
        f4 acc = {0.f, 0.f, 0.f, 0.f};
#pragma unroll
        for (int i = 0; i < 6; ++i) {
            acc += f[i].x * w[i][0];
            acc += f[i].y * w[i][1];
            acc += f[i].z * w[i][2];
            acc += f[i].w * w[i][3];
        }
        // fold 4 col-partials -> 1 per lane (2 shfl), then 4-step butterfly
        {
            const bool b0 = lane & 1;
            float s0 = b0 ? acc.x : acc.z;
            float s1 = b0 ? acc.y : acc.w;
            float r0 = __shfl_xor(s0, 1, 64);
            float r1 = __shfl_xor(s1, 1, 64);
            float k0 = (b0 ? acc.z : acc.x) + r0;
            float k1 = (b0 ? acc.w : acc.y) + r1;
            const bool b1 = lane & 2;
            float s = b1 ? k0 : k1;
            float r = __shfl_xor(s, 2, 64);
            float v = (b1 ? k1 : k0) + r;
            v += __shfl_xor(v, 4, 64);
            v += __shfl_xor(v, 8, 64);
            v += __shfl_xor(v, 16, 64);
            v += __shfl_xor(v, 32, 64);
            if (lane < 4) {
                int cl = 2 * (lane & 1) + ((lane >> 1) & 1);   // lane -> col within group
                x1[(size_t)row * HID + c0 + cl] = v * nsrc[row];
            }
        }
#pragma unroll
        for (int i = 0; i < 6; ++i) f[i] = g[i];
    }
}

// ---- layer-1 aggregation: m1[dst][4q..4q+4) = relu(ndst*sum_e x1[src] + b1) ----
__global__ void agg1_kernel(const int* __restrict__ offs, const int* __restrict__ cnt,
                            const int* __restrict__ ssrc, const float* __restrict__ x1,
                            const float* __restrict__ ndst, const float* __restrict__ b1,
                            float* __restrict__ m1) {
    int t = blockIdx.x * blockDim.x + threadIdx.x;
    if (t >= NN * 4) return;
    int dst = t >> 2, q = t & 3;
    int st = offs[dst], deg = cnt[dst];
    f4 acc = {0.f, 0.f, 0.f, 0.f};
    for (int e = 0; e < deg; ++e) {
        int s = ssrc[st + e];
        acc += *(const f4*)(x1 + (size_t)s * HID + 4 * q);
    }
    float nd = ndst[dst];
    const f4 b = *(const f4*)(b1 + 4 * q);
    f4 h = acc * nd + b;
    h.x = fmaxf(h.x, 0.f); h.y = fmaxf(h.y, 0.f);
    h.z = fmaxf(h.z, 0.f); h.w = fmaxf(h.w, 0.f);
    *(f4*)(m1 + (size_t)dst * HID + 4 * q) = h;
}

// ---- layer-2 dense: x2 = (m1 @ W2) * nsrc  (m1 already relu'd+normed) ----
__global__ void layer2_kernel(const float* __restrict__ m1, const float* __restrict__ nsrc,
                              const float* __restrict__ W2, float* __restrict__ x2) {
    int i = blockIdx.x * blockDim.x + threadIdx.x;
    if (i >= NN) return;
    float h[16];
#pragma unroll
    for (int p = 0; p < 4; ++p) {
        f4 v = *(const f4*)(m1 + (size_t)i * HID + 4 * p);
        h[4 * p] = v.x; h[4 * p + 1] = v.y; h[4 * p + 2] = v.z; h[4 * p + 3] = v.w;
    }
    float ns = nsrc[i];
    float o[OUTF];
#pragma unroll
    for (int c = 0; c < OUTF; ++c) {
        float a = 0.f;
#pragma unroll
        for (int j = 0; j < HID; ++j) a = fmaf(h[j], W2[j * OUTF + c], a);
        o[c] = a * ns;
    }
    f4 v0 = {o[0], o[1], o[2], o[3]};
    st_f4u(x2 + (size_t)i * OUTF, v0);
    x2[(size_t)i * OUTF + 4] = o[4];
    x2[(size_t)i * OUTF + 5] = o[5];
    x2[(size_t)i * OUTF + 6] = o[6];
}

// ---- layer-2 aggregation + epilogue: out = ndst*sum_e x2[src] + b2 ----
__global__ void agg2_kernel(const int* __restrict__ offs, const int* __restrict__ cnt,
                            const int* __restrict__ ssrc, const float* __restrict__ x2,
                            const float* __restrict__ ndst, const float* __restrict__ b2,
                            float* __restrict__ out) {
    int t = blockIdx.x * blockDim.x + threadIdx.x;
    if (t >= NN * 2) return;
    int dst = t >> 1, q = t & 1;
    int st = offs[dst], deg = cnt[dst];
    f4 acc = {0.f, 0.f, 0.f, 0.f};
    for (int e = 0; e < deg; ++e) {
        int s = ssrc[st + e];
        acc += ld_f4u(x2 + (size_t)s * OUTF + 4 * q);   // q=1: 4th elem is junk, never stored
    }
    float nd = ndst[dst];
    if (q == 0) {
        f4 b = {b2[0], b2[1], b2[2], b2[3]};
        f4 r = acc * nd + b;
        st_f4u(out + (size_t)dst * OUTF, r);
    } else {
        out[(size_t)dst * OUTF + 4] = acc.x * nd + b2[4];
        out[(size_t)dst * OUTF + 5] = acc.y * nd + b2[5];
        out[(size_t)dst * OUTF + 6] = acc.z * nd + b2[6];
    }
}

extern "C" void kernel_launch(void* const* d_in, const int* in_sizes, int n_in,
                              void* d_out, int out_size, void* d_ws, size_t ws_size,
                              hipStream_t stream) {
    const float* feat = (const float*)d_in[0];
    const int*   ei   = (const int*)d_in[1];     // [2, NE] int32
    const float* W1   = (const float*)d_in[2];
    const float* b1   = (const float*)d_in[3];
    const float* W2   = (const float*)d_in[4];
    const float* b2   = (const float*)d_in[5];
    float*       out  = (float*)d_out;

    // workspace layout (4B units): total ~28 MB
    int*   sorted_src = (int*)d_ws;              // [NE]
    int*   cnt_src    = sorted_src + NE;         // [NN]
    int*   cnt_dst    = cnt_src + NN;            // [NN]
    int*   offs       = cnt_dst + NN;            // [NN]
    int*   cursor     = offs + NN;               // [NN]
    float* nsrc       = (float*)(cursor + NN);   // [NN]
    float* ndst       = nsrc + NN;               // [NN]
    float* x1         = ndst + NN;               // [16*NN]; reused as x2 [7*NN] later
    float* m1         = x1 + (size_t)16 * NN;    // [16*NN]
    float* x2         = x1;                      // x1 dead after agg1

    hipMemsetAsync(cnt_src, 0, (size_t)2 * NN * sizeof(int), stream);

    count_kernel<<<(NE + 255) / 256, 256, 0, stream>>>(ei, cnt_src, cnt_dst);
    norm_kernel<<<(NN + 255) / 256, 256, 0, stream>>>(cnt_src, cnt_dst, nsrc, ndst);
    scan_kernel<<<1, 1024, 0, stream>>>(cnt_dst, offs, cursor);
    fill_kernel<<<(NE + 255) / 256, 256, 0, stream>>>(ei, cursor, sorted_src);

    const int grid1 = 1563, rpb = 64;            // 1563*64 >= 100000
    gemm1_kernel<<<grid1, 256, 0, stream>>>(feat, W1, nsrc, x1, rpb);

    agg1_kernel<<<(NN * 4 + 255) / 256, 256, 0, stream>>>(offs, cnt_dst, sorted_src, x1, ndst, b1, m1);
    layer2_kernel<<<(NN + 255) / 256, 256, 0, stream>>>(m1, nsrc, W2, x2);
    agg2_kernel<<<(NN * 2 + 255) / 256, 256, 0, stream>>>(offs, cnt_dst, sorted_src, x2, ndst, b2, out);
}

// Round 3
// 1442.770 us; speedup vs baseline: 1.2820x; 1.0715x over previous
//
#include <hip/hip_runtime.h>

#define NN   100000
#define NE   3200000
#define K_IN 1433
#define HID  16
#define OUTF 7

#define SCAN_CHUNK 512
#define SCAN_NB    196   // 196*512 = 100352 >= NN

typedef float f4 __attribute__((ext_vector_type(4)));

__device__ __forceinline__ f4 ld_f4u(const float* p) { f4 r; __builtin_memcpy(&r, p, 16); return r; }
__device__ __forceinline__ void st_f4u(float* p, f4 v) { __builtin_memcpy(p, &v, 16); }

// ---------------- CSR build ----------------
__global__ void count_kernel(const int* __restrict__ ei,
                             int* __restrict__ cnt_src, int* __restrict__ cnt_dst) {
    int e = blockIdx.x * blockDim.x + threadIdx.x;
    if (e < NE) {
        atomicAdd(&cnt_src[ei[e]], 1);
        atomicAdd(&cnt_dst[ei[NE + e]], 1);
    }
}

__global__ void norm_kernel(const int* __restrict__ cnt_src, const int* __restrict__ cnt_dst,
                            float* __restrict__ nsrc, float* __restrict__ ndst) {
    int i = blockIdx.x * blockDim.x + threadIdx.x;
    if (i < NN) {
        nsrc[i] = rsqrtf(fmaxf((float)cnt_src[i], 1.0f));
        ndst[i] = rsqrtf(fmaxf((float)cnt_dst[i], 1.0f));
    }
}

// phase A: per-block (512-elem chunk) sums of cnt_dst
__global__ __launch_bounds__(256) void scanA_kernel(const int* __restrict__ cnt,
                                                    int* __restrict__ partials) {
    __shared__ int sh[256];
    int b = blockIdx.x, t = threadIdx.x;
    int i0 = b * SCAN_CHUNK + 2 * t;
    int v0 = (i0 < NN) ? cnt[i0] : 0;
    int v1 = (i0 + 1 < NN) ? cnt[i0 + 1] : 0;
    int s = v0 + v1;
    // wave reduce then LDS
    for (int d = 1; d < 64; d <<= 1) s += __shfl_xor(s, d, 64);
    if ((t & 63) == 0) sh[t >> 6] = s;
    __syncthreads();
    if (t == 0) partials[b] = sh[0] + sh[1] + sh[2] + sh[3];
}

// phase B: single block exclusive-scans the 196 partials
__global__ __launch_bounds__(256) void scanB_kernel(const int* __restrict__ partials,
                                                    int* __restrict__ base) {
    __shared__ int sh[256];
    int t = threadIdx.x;
    int v = (t < SCAN_NB) ? partials[t] : 0;
    sh[t] = v;
    __syncthreads();
    for (int d = 1; d < 256; d <<= 1) {
        int x = (t >= d) ? sh[t - d] : 0;
        __syncthreads();
        sh[t] += x;
        __syncthreads();
    }
    if (t < SCAN_NB) base[t] = sh[t] - v;   // exclusive
}

// phase C: rescan each chunk, add base, write offs + cursor
__global__ __launch_bounds__(256) void scanC_kernel(const int* __restrict__ cnt,
                                                    const int* __restrict__ base,
                                                    int* __restrict__ offs, int* __restrict__ cursor) {
    __shared__ int sh[256];
    int b = blockIdx.x, t = threadIdx.x;
    int i0 = b * SCAN_CHUNK + 2 * t;
    int v0 = (i0 < NN) ? cnt[i0] : 0;
    int v1 = (i0 + 1 < NN) ? cnt[i0 + 1] : 0;
    int s = v0 + v1;
    sh[t] = s;
    __syncthreads();
    for (int d = 1; d < 256; d <<= 1) {
        int x = (t >= d) ? sh[t - d] : 0;
        __syncthreads();
        sh[t] += x;
        __syncthreads();
    }
    int excl = sh[t] - s + base[b];
    if (i0 < NN)     { offs[i0] = excl;      cursor[i0] = excl; }
    if (i0 + 1 < NN) { offs[i0 + 1] = excl + v0; cursor[i0 + 1] = excl + v0; }
}

__global__ void fill_kernel(const int* __restrict__ ei, int* __restrict__ cursor,
                            int* __restrict__ sorted_src) {
    int e = blockIdx.x * blockDim.x + threadIdx.x;
    if (e < NE) {
        int d = ei[NE + e];
        int slot = atomicAdd(&cursor[d], 1);
        sorted_src[slot] = ei[e];
    }
}

// ---------------- layer-1 GEMM: x1 = (feat * nsrc) @ W1 ----------------
// Block = 4 waves; wave w owns cols [4w,4w+4). Lane l owns k in {4l+256i}.
// w slice = 96 VGPRs; NO explicit double-buffer (round-2 version spilled
// past the 168-VGPR cap of launch_bounds(256,3); compiler pipelines rows
// itself within the budget). 7-shuffle butterfly, disjoint stores.
__global__ __launch_bounds__(256, 3) void gemm1_kernel(
    const float* __restrict__ feat, const float* __restrict__ W1,
    const float* __restrict__ nsrc, float* __restrict__ x1)
{
    const int tid  = threadIdx.x;
    const int lane = tid & 63;
    const int wv   = tid >> 6;
    const int c0   = 4 * wv;

    const int kb5 = 1280 + 4 * lane;                       // i=5 nominal base
    const int kc5 = (kb5 > K_IN - 4) ? (K_IN - 4) : kb5;   // clamped in-row load base

    f4 w[6][4];
#pragma unroll
    for (int i = 0; i < 5; ++i) {
        int kb = 4 * lane + 256 * i;
#pragma unroll
        for (int d = 0; d < 4; ++d)
            w[i][d] = ld_f4u(W1 + (size_t)(kb + d) * HID + c0);
    }
#pragma unroll
    for (int d = 0; d < 4; ++d) {
        int keff = kc5 + d;
        f4 z = {0.f, 0.f, 0.f, 0.f};
        w[5][d] = (keff >= kb5 && keff < K_IN) ? ld_f4u(W1 + (size_t)keff * HID + c0) : z;
    }

    const int row0 = blockIdx.x * 32;
    const int row1 = min(row0 + 32, NN);

    for (int row = row0; row < row1; ++row) {
        const float* fp = feat + (size_t)row * K_IN;
        f4 f[6];
#pragma unroll
        for (int i = 0; i < 5; ++i) f[i] = ld_f4u(fp + 4 * lane + 256 * i);
        f[5] = ld_f4u(fp + kc5);

        f4 acc = {0.f, 0.f, 0.f, 0.f};
#pragma unroll
        for (int i = 0; i < 6; ++i) {
            acc += f[i].x * w[i][0];
            acc += f[i].y * w[i][1];
            acc += f[i].z * w[i][2];
            acc += f[i].w * w[i][3];
        }
        // fold 4 col-partials -> 1 per lane (2 shfl), then 4-step butterfly
        const bool b0 = lane & 1;
        float s0 = b0 ? acc.x : acc.z;
        float s1 = b0 ? acc.y : acc.w;
        float r0 = __shfl_xor(s0, 1, 64);
        float r1 = __shfl_xor(s1, 1, 64);
        float k0 = (b0 ? acc.z : acc.x) + r0;
        float k1 = (b0 ? acc.w : acc.y) + r1;
        const bool b1 = lane & 2;
        float s = b1 ? k0 : k1;
        float r = __shfl_xor(s, 2, 64);
        float v = (b1 ? k1 : k0) + r;
        v += __shfl_xor(v, 4, 64);
        v += __shfl_xor(v, 8, 64);
        v += __shfl_xor(v, 16, 64);
        v += __shfl_xor(v, 32, 64);
        if (lane < 4) {
            int cl = 2 * (lane & 1) + ((lane >> 1) & 1);   // lane -> col within group
            x1[(size_t)row * HID + c0 + cl] = v * nsrc[row];
        }
    }
}

// ---- layer-1 aggregation: m1[dst][4q..4q+4) = relu(ndst*sum_e x1[src] + b1) ----
__global__ void agg1_kernel(const int* __restrict__ offs, const int* __restrict__ cnt,
                            const int* __restrict__ ssrc, const float* __restrict__ x1,
                            const float* __restrict__ ndst, const float* __restrict__ b1,
                            float* __restrict__ m1) {
    int t = blockIdx.x * blockDim.x + threadIdx.x;
    if (t >= NN * 4) return;
    int dst = t >> 2, q = t & 3;
    int st = offs[dst], deg = cnt[dst];
    f4 acc = {0.f, 0.f, 0.f, 0.f};
    for (int e = 0; e < deg; ++e) {
        int s = ssrc[st + e];
        acc += *(const f4*)(x1 + (size_t)s * HID + 4 * q);
    }
    float nd = ndst[dst];
    const f4 b = *(const f4*)(b1 + 4 * q);
    f4 h = acc * nd + b;
    h.x = fmaxf(h.x, 0.f); h.y = fmaxf(h.y, 0.f);
    h.z = fmaxf(h.z, 0.f); h.w = fmaxf(h.w, 0.f);
    *(f4*)(m1 + (size_t)dst * HID + 4 * q) = h;
}

// ---- layer-2 dense: x2 = (m1 @ W2) * nsrc ----
__global__ void layer2_kernel(const float* __restrict__ m1, const float* __restrict__ nsrc,
                              const float* __restrict__ W2, float* __restrict__ x2) {
    int i = blockIdx.x * blockDim.x + threadIdx.x;
    if (i >= NN) return;
    float h[16];
#pragma unroll
    for (int p = 0; p < 4; ++p) {
        f4 v = *(const f4*)(m1 + (size_t)i * HID + 4 * p);
        h[4 * p] = v.x; h[4 * p + 1] = v.y; h[4 * p + 2] = v.z; h[4 * p + 3] = v.w;
    }
    float ns = nsrc[i];
    float o[OUTF];
#pragma unroll
    for (int c = 0; c < OUTF; ++c) {
        float a = 0.f;
#pragma unroll
        for (int j = 0; j < HID; ++j) a = fmaf(h[j], W2[j * OUTF + c], a);
        o[c] = a * ns;
    }
    f4 v0 = {o[0], o[1], o[2], o[3]};
    st_f4u(x2 + (size_t)i * OUTF, v0);
    x2[(size_t)i * OUTF + 4] = o[4];
    x2[(size_t)i * OUTF + 5] = o[5];
    x2[(size_t)i * OUTF + 6] = o[6];
}

// ---- layer-2 aggregation + epilogue: out = ndst*sum_e x2[src] + b2 ----
__global__ void agg2_kernel(const int* __restrict__ offs, const int* __restrict__ cnt,
                            const int* __restrict__ ssrc, const float* __restrict__ x2,
                            const float* __restrict__ ndst, const float* __restrict__ b2,
                            float* __restrict__ out) {
    int t = blockIdx.x * blockDim.x + threadIdx.x;
    if (t >= NN * 2) return;
    int dst = t >> 1, q = t & 1;
    int st = offs[dst], deg = cnt[dst];
    f4 acc = {0.f, 0.f, 0.f, 0.f};
    for (int e = 0; e < deg; ++e) {
        int s = ssrc[st + e];
        acc += ld_f4u(x2 + (size_t)s * OUTF + 4 * q);   // q=1: 4th elem junk, never stored
    }
    float nd = ndst[dst];
    if (q == 0) {
        f4 b = {b2[0], b2[1], b2[2], b2[3]};
        f4 r = acc * nd + b;
        st_f4u(out + (size_t)dst * OUTF, r);
    } else {
        out[(size_t)dst * OUTF + 4] = acc.x * nd + b2[4];
        out[(size_t)dst * OUTF + 5] = acc.y * nd + b2[5];
        out[(size_t)dst * OUTF + 6] = acc.z * nd + b2[6];
    }
}

extern "C" void kernel_launch(void* const* d_in, const int* in_sizes, int n_in,
                              void* d_out, int out_size, void* d_ws, size_t ws_size,
                              hipStream_t stream) {
    const float* feat = (const float*)d_in[0];
    const int*   ei   = (const int*)d_in[1];     // [2, NE] int32
    const float* W1   = (const float*)d_in[2];
    const float* b1   = (const float*)d_in[3];
    const float* W2   = (const float*)d_in[4];
    const float* b2   = (const float*)d_in[5];
    float*       out  = (float*)d_out;

    // workspace layout (4B units)
    int*   sorted_src = (int*)d_ws;              // [NE]
    int*   cnt_src    = sorted_src + NE;         // [NN]
    int*   cnt_dst    = cnt_src + NN;            // [NN]
    int*   offs       = cnt_dst + NN;            // [NN]
    int*   cursor     = offs + NN;               // [NN]
    int*   partials   = cursor + NN;             // [256]
    int*   base       = partials + 256;          // [256]
    float* nsrc       = (float*)(base + 256);    // [NN]
    float* ndst       = nsrc + NN;               // [NN]
    float* x1         = ndst + NN;               // [16*NN]; reused as x2 later
    float* m1         = x1 + (size_t)16 * NN;    // [16*NN]
    float* x2         = x1;                      // x1 dead after agg1

    hipMemsetAsync(cnt_src, 0, (size_t)2 * NN * sizeof(int), stream);

    count_kernel<<<(NE + 255) / 256, 256, 0, stream>>>(ei, cnt_src, cnt_dst);
    norm_kernel<<<(NN + 255) / 256, 256, 0, stream>>>(cnt_src, cnt_dst, nsrc, ndst);
    scanA_kernel<<<SCAN_NB, 256, 0, stream>>>(cnt_dst, partials);
    scanB_kernel<<<1, 256, 0, stream>>>(partials, base);
    scanC_kernel<<<SCAN_NB, 256, 0, stream>>>(cnt_dst, base, offs, cursor);
    fill_kernel<<<(NE + 255) / 256, 256, 0, stream>>>(ei, cursor, sorted_src);

    gemm1_kernel<<<(NN + 31) / 32, 256, 0, stream>>>(feat, W1, nsrc, x1);

    agg1_kernel<<<(NN * 4 + 255) / 256, 256, 0, stream>>>(offs, cnt_dst, sorted_src, x1, ndst, b1, m1);
    layer2_kernel<<<(NN + 255) / 256, 256, 0, stream>>>(m1, nsrc, W2, x2);
    agg2_kernel<<<(NN * 2 + 255) / 256, 256, 0, stream>>>(offs, cnt_dst, sorted_src, x2, ndst, b2, out);
}